// Round 6
// baseline (169.608 us; speedup 1.0000x reference)
//
#include <hip/hip_runtime.h>
#include <math.h>

#define SEQ_L 2048
#define DM 1024
#define NH 16
#define HD 64
#define NB 2
#define KD 1024   // GEMM K
#define ND 1024   // GEMM N

typedef __bf16 bf16;
typedef __bf16 bf16x8 __attribute__((ext_vector_type(8)));
typedef __bf16 bf16x4 __attribute__((ext_vector_type(4)));
typedef __bf16 bf16x2 __attribute__((ext_vector_type(2)));
typedef float f32x4 __attribute__((ext_vector_type(4)));

// ---------------- jax threefry2x32, key = (0, 42); partitionable random_bits ----------------
__device__ inline uint32_t rotl32(uint32_t v, int n) { return (v << n) | (v >> (32 - n)); }

__device__ inline void threefry(uint32_t x0, uint32_t x1, uint32_t* o0, uint32_t* o1) {
  const uint32_t ks0 = 0u, ks1 = 42u, ks2 = 0u ^ 42u ^ 0x1BD11BDAu;
  x0 += ks0; x1 += ks1;
#define TF_R(rr) { x0 += x1; x1 = rotl32(x1, rr); x1 ^= x0; }
  TF_R(13) TF_R(15) TF_R(26) TF_R(6)
  x0 += ks1; x1 += ks2 + 1u;
  TF_R(17) TF_R(29) TF_R(16) TF_R(24)
  x0 += ks2; x1 += ks0 + 2u;
  TF_R(13) TF_R(15) TF_R(26) TF_R(6)
  x0 += ks0; x1 += ks1 + 3u;
  TF_R(17) TF_R(29) TF_R(16) TF_R(24)
  x0 += ks1; x1 += ks2 + 4u;
  TF_R(13) TF_R(15) TF_R(26) TF_R(6)
  x0 += ks2; x1 += ks0 + 5u;
#undef TF_R
  *o0 = x0; *o1 = x1;
}

// jax_threefry_partitionable=True: counter (hi=0, lo=flat_idx), bits = o0 ^ o1.
__device__ inline int rand_col(int i, int s) {
  uint32_t o0, o1;
  threefry(0u, (uint32_t)(2 * i + s), &o0, &o1);
  uint32_t bits = o0 ^ o1;
  float u = __uint_as_float((bits >> 9) | 0x3f800000u) - 1.0f;
  return (int)floorf(u * (float)(i + 1));
}

// ---------------- prep: conversions + ctab + rope cos/sin table ----------------
__global__ void prep_kernel(const float* __restrict__ x,
                            const float* __restrict__ w0, const float* __restrict__ w1,
                            const float* __restrict__ w2, const float* __restrict__ w3,
                            const float* __restrict__ freqs,
                            bf16* __restrict__ xb,
                            bf16* __restrict__ o0, bf16* __restrict__ o1,
                            bf16* __restrict__ o2, bf16* __restrict__ o3,
                            int* __restrict__ ctab, float2* __restrict__ rtab) {
  const int bx = blockIdx.x;
  const int t = threadIdx.x;
  if (bx < 8192) {
    const float* src;
    bf16* dst;
    int idx;
    if (bx < 4096) { src = x; dst = xb; idx = bx * 256 + t; }
    else {
      int widx = bx - 4096;
      int wsel = widx >> 10;
      switch (wsel) {
        case 0: src = w0; dst = o0; break;
        case 1: src = w1; dst = o1; break;
        case 2: src = w2; dst = o2; break;
        default: src = w3; dst = o3; break;
      }
      idx = (widx & 1023) * 256 + t;
    }
    float4 vv = ((const float4*)src)[idx];
    bf16x4 ov;
    ov[0] = (bf16)vv.x; ov[1] = (bf16)vv.y; ov[2] = (bf16)vv.z; ov[3] = (bf16)vv.w;
    *(bf16x4*)(dst + (size_t)idx * 4) = ov;
    return;
  }
  if (bx < 8200) {
    const int i = (bx - 8192) * 256 + t;    // 0..2047
    int cols[11]; int nc = 0;
    if (i >= 1) {
      int lo = i - 7; if (lo < 0) lo = 0;
      for (int j = lo; j <= i; ++j) cols[nc++] = j;
      if (lo > 0) cols[nc++] = 0;
#pragma unroll
      for (int s = 0; s < 2; ++s) {
        int rj = rand_col(i, s);
        bool dup = false;
        for (int c2 = 0; c2 < nc; ++c2) dup |= (cols[c2] == rj);
        if (!dup) cols[nc++] = rj;
      }
    }
    for (int c2 = nc; c2 < 11; ++c2) cols[c2] = -1;
#pragma unroll
    for (int c2 = 0; c2 < 11; ++c2) ctab[i * 12 + c2] = cols[c2];
    ctab[i * 12 + 11] = nc;
    return;
  }
  const int idx = (bx - 8200) * 256 + t;    // 0..65535
  float s, c;
  sincosf(freqs[idx], &s, &c);
  rtab[idx] = make_float2(c, s);
}

// ---------------- GEMM common ----------------
__device__ inline void gld16(const bf16* g, bf16* l) {
  __builtin_amdgcn_global_load_lds((const __attribute__((address_space(1))) void*)g,
                                   (__attribute__((address_space(3))) void*)l, 16, 0, 0);
}

// ---- fused QKV GEMM: one block = 64(m) x 64(n) tile of q, k AND v (shared A staging).
// v3: BK=32 DOUBLE-buffer with STATIC named buffers (T3-minimum, m248v2-measured form).
// Per tile: stage(kt+1 -> other buf) issued FIRST, then ds_read+MFMA on current buf,
// then ONE __syncthreads. The barrier's vmcnt(0) drain now waits on loads that had the
// whole compute phase (plus 3 co-resident blocks) to land, instead of being naked.
// R1's regression was runtime buffer indexing (compiler couldn't disambiguate -> early
// drain); static As0/As1 etc. fixes that. LDS stays 32 KB -> 4 blocks/CU preserved.
// K-accumulation: ascending 32-chunks, identical order to the BK=64 version ->
// bit-identical output. Safety: only __syncthreads (full drain) -- race-free.
__global__ __launch_bounds__(256, 4) void qkv_gemm_kernel(
    const bf16* __restrict__ xb, const bf16* __restrict__ wqb, const bf16* __restrict__ wkb,
    const bf16* __restrict__ wvb, bf16* __restrict__ qb, bf16* __restrict__ kb, bf16* __restrict__ vb,
    const float2* __restrict__ rtab) {
  __shared__ __align__(16) bf16 As0[64 * 32], As1[64 * 32];        // 2 x 4 KB
  __shared__ __align__(16) bf16 Bs0[3][64 * 32], Bs1[3][64 * 32];  // 2 x 12 KB
  bf16* Ds[3] = {qb, kb, vb};

  const int t = threadIdx.x;
  const int lane = t & 63;
  const int w = t >> 6;
  const int wm = (w >> 1) * 32;     // wave tile: 32(m) x 32(n)
  const int wn = (w & 1) * 32;
  const int m0 = blockIdx.x * 64;
  const int n0 = blockIdx.y * 64;
  const int l15 = lane & 15;
  const int kq = lane >> 4;         // 0..3 = K chunk within BK=32

  // staging geometry (BK=32): slot t -> row r0 = t>>2, phys chunk t&3 holds global
  // chunk (t&3)^((r0>>1)&3)   [swizzle verified conflict-free: R1/R3 SQ_LDS_BANK_CONFLICT==0]
  const int r0 = t >> 2;
  const int chs = (t & 3) ^ ((r0 >> 1) & 3);
  const size_t soff = (size_t)r0 * KD + chs * 8;
  const bf16* pA  = xb  + (size_t)m0 * KD + soff;
  const bf16* pB0 = wqb + (size_t)n0 * KD + soff;
  const bf16* pB1 = wkb + (size_t)n0 * KD + soff;
  const bf16* pB2 = wvb + (size_t)n0 * KD + soff;
  const int t8 = t * 8;

  f32x4 acc[3][2][2] = {};

  auto stage = [&](int kt, bf16* A, bf16* B0, bf16* B1, bf16* B2) {
    const int koff = kt * 32;
    gld16(pA + koff, A + t8);
    gld16(pB0 + koff, B0 + t8);
    gld16(pB1 + koff, B1 + t8);
    gld16(pB2 + koff, B2 + t8);
  };
  auto comp = [&](const bf16* A, const bf16* B0, const bf16* B1, const bf16* B2) {
    bf16x8 af[2];
#pragma unroll
    for (int mt = 0; mt < 2; ++mt) {
      const int row = wm + mt * 16 + l15;
      af[mt] = *(const bf16x8*)(A + row * 32 + ((kq ^ ((row >> 1) & 3)) * 8));
    }
    const bf16* Bp[3] = {B0, B1, B2};
#pragma unroll
    for (int j = 0; j < 3; ++j) {
      bf16x8 bfr[2];
#pragma unroll
      for (int nt = 0; nt < 2; ++nt) {
        const int row = wn + nt * 16 + l15;
        bfr[nt] = *(const bf16x8*)(Bp[j] + row * 32 + ((kq ^ ((row >> 1) & 3)) * 8));
      }
#pragma unroll
      for (int mt = 0; mt < 2; ++mt)
#pragma unroll
        for (int nt = 0; nt < 2; ++nt)
          acc[j][mt][nt] = __builtin_amdgcn_mfma_f32_16x16x32_bf16(af[mt], bfr[nt], acc[j][mt][nt], 0, 0, 0);
    }
  };

  // prologue: tile 0 into buffer 0 (only exposed drain of the loop)
  stage(0, As0, &Bs0[0][0], &Bs0[1][0], &Bs0[2][0]);
  __syncthreads();

  for (int kt = 0; kt < 32; kt += 2) {
    stage(kt + 1, As1, &Bs1[0][0], &Bs1[1][0], &Bs1[2][0]);       // kt+1 <= 31 always
    comp(As0, &Bs0[0][0], &Bs0[1][0], &Bs0[2][0]);
    __syncthreads();
    if (kt + 2 < 32) stage(kt + 2, As0, &Bs0[0][0], &Bs0[1][0], &Bs0[2][0]);
    comp(As1, &Bs1[0][0], &Bs1[1][0], &Bs1[2][0]);
    __syncthreads();
  }

  // C/D layout: col = lane&15, row = (lane>>4)*4 + reg   [verified m89]
  const int colb = n0 + wn + l15;
  const int rowb = m0 + wm + (lane >> 4) * 4;
  const int odd = l15 & 1;
#pragma unroll
  for (int j = 0; j < 3; ++j) {
    bf16* D = Ds[j];
    const bool dorope = (j < 2);
#pragma unroll
    for (int mt = 0; mt < 2; ++mt)
#pragma unroll
      for (int nt = 0; nt < 2; ++nt) {
        const int col = colb + nt * 16;
        const int jj = (col & 63) >> 1;
#pragma unroll
        for (int rr = 0; rr < 4; ++rr) {
          float val = acc[j][mt][nt][rr];
          float other = __shfl_xor(val, 1);    // partner column value
          if (!odd) {
            const int row = rowb + mt * 16 + rr;
            float lo, hi;
            if (dorope) {
              float2 cs = rtab[(row & (SEQ_L - 1)) * 32 + jj];
              lo = val * cs.x - other * cs.y;  // out_re
              hi = val * cs.y + other * cs.x;  // out_im
            } else { lo = val; hi = other; }
            bf16x2 p; p[0] = (bf16)lo; p[1] = (bf16)hi;
            *(bf16x2*)(D + (size_t)row * ND + col) = p;
          }
        }
      }
  }
}

// ---- out-projection GEMM: 64x128 tile, BK=32 static double-buffer (same recipe) ----
// LDS 2 x (4KB A + 8KB B) = 24 KB; grid (64,8) = 512 blocks @ 2/CU.
// Blocks x==0 / x==32 first materialize row-0 attention output from (pm,pz,pv).
__global__ __launch_bounds__(256, 2) void out_gemm_kernel(
    bf16* __restrict__ ab, const bf16* __restrict__ wob, float* __restrict__ out,
    const float* __restrict__ pm, const float* __restrict__ pz, const float* __restrict__ pv) {
  const int t = threadIdx.x;
  const int m0 = blockIdx.x * 64;
  const int n0 = blockIdx.y * 128;

  if (blockIdx.x == 0 || blockIdx.x == 32) {
    const int b = blockIdx.x == 0 ? 0 : 1;
#pragma unroll
    for (int e = t; e < DM; e += 256) {
      const int h = e >> 6, d = e & 63;
      const int base = b * 128 + h * 8;
      float M = -1e30f;
#pragma unroll
      for (int c = 0; c < 8; ++c) M = fmaxf(M, pm[base + c]);
      float Z = 0.f, od = 0.f;
#pragma unroll
      for (int c = 0; c < 8; ++c) {
        float sc = __expf(pm[base + c] - M);
        Z += pz[base + c] * sc;
        od += pv[(base + c) * 64 + d] * sc;
      }
      ab[(size_t)b * SEQ_L * DM + e] = (bf16)(od / Z);
    }
    __syncthreads();   // drain stores before staging reads the same row
  }

  __shared__ __align__(16) bf16 Ao0[64 * 32], Ao1[64 * 32];     // 2 x 4 KB
  __shared__ __align__(16) bf16 Bo0[128 * 32], Bo1[128 * 32];   // 2 x 8 KB
  const int lane = t & 63;
  const int wave = t >> 6;
  const int wm = (wave >> 1) * 32;
  const int wn = (wave & 1) * 64;
  const int l15 = lane & 15;
  const int kq = lane >> 4;

  // staging geometry: A 256 slots (1/thread, rows 0..63); B 512 slots (2/thread, rows 0..127)
  const int r0 = t >> 2;
  const int chs = (t & 3) ^ ((r0 >> 1) & 3);
  const size_t soff = (size_t)r0 * KD + chs * 8;
  const bf16* pA  = ab  + (size_t)m0 * KD + soff;
  const bf16* pB0 = wob + (size_t)n0 * KD + soff;
  const bf16* pB1 = pB0 + (size_t)64 * KD;     // rows 64..127, same swizzle phase
  const int t8 = t * 8;

  f32x4 acc[2][4] = {};

  auto stage = [&](int kt, bf16* A, bf16* B) {
    const int koff = kt * 32;
    gld16(pA + koff, A + t8);
    gld16(pB0 + koff, B + t8);
    gld16(pB1 + koff, B + 2048 + t8);
  };
  auto comp = [&](const bf16* A, const bf16* B) {
    bf16x8 af[2], bfr[4];
#pragma unroll
    for (int mt = 0; mt < 2; ++mt) {
      const int row = wm + mt * 16 + l15;
      af[mt] = *(const bf16x8*)(A + row * 32 + ((kq ^ ((row >> 1) & 3)) * 8));
    }
#pragma unroll
    for (int nt = 0; nt < 4; ++nt) {
      const int row = wn + nt * 16 + l15;
      bfr[nt] = *(const bf16x8*)(B + row * 32 + ((kq ^ ((row >> 1) & 3)) * 8));
    }
#pragma unroll
    for (int mt = 0; mt < 2; ++mt)
#pragma unroll
      for (int nt = 0; nt < 4; ++nt)
        acc[mt][nt] = __builtin_amdgcn_mfma_f32_16x16x32_bf16(af[mt], bfr[nt], acc[mt][nt], 0, 0, 0);
  };

  stage(0, Ao0, Bo0);
  __syncthreads();

  for (int kt = 0; kt < 32; kt += 2) {
    stage(kt + 1, Ao1, Bo1);
    comp(Ao0, Bo0);
    __syncthreads();
    if (kt + 2 < 32) stage(kt + 2, Ao0, Bo0);
    comp(Ao1, Bo1);
    __syncthreads();
  }

  const int colb = n0 + wn + l15;
  const int rowb = m0 + wm + (lane >> 4) * 4;
#pragma unroll
  for (int mt = 0; mt < 2; ++mt)
#pragma unroll
    for (int nt = 0; nt < 4; ++nt)
#pragma unroll
      for (int rr = 0; rr < 4; ++rr)
        out[(size_t)(rowb + mt * 16 + rr) * ND + colb + nt * 16] = acc[mt][nt][rr];
}

// ---------------- attention ----------------
// grid (1280, 1), 256 threads.
//  bx < 256  : row-0 partials per (b, h, 256-col chunk) -> pm/pz/pv (dispatched FIRST: no tail).
//  bx >= 256 : sparse rows; wave handles one row i for ALL 16 heads (2KB wave-loads).
//  T14-lite: K quads prefetched up-front; V loads issued AFTER the QK dots so the
//  allocator reuses K's ~88 VGPRs for V -> __launch_bounds__(256,3) = 12 waves/CU.
__global__ __launch_bounds__(256, 3) void attn_kernel(const bf16* __restrict__ q, const bf16* __restrict__ k,
                                                      const bf16* __restrict__ v, bf16* __restrict__ o,
                                                      const int* __restrict__ ctab,
                                                      float* __restrict__ pm, float* __restrict__ pz,
                                                      float* __restrict__ pv) {
  const int t = threadIdx.x;
  const int lane = t & 63;
  const int w = t >> 6;

  __shared__ float sbuf[256];
  __shared__ float redm[4], redz[4];
  __shared__ float part[4][64];

  if (blockIdx.x >= 256) {
    const int sbx = blockIdx.x - 256;               // 0..1023
    const int b = sbx >> 9;
    const int tt = sbx & 511;
    const int tile = ((tt & 7) << 6) + (tt >> 3);   // XCD swizzle
    const int i = tile * 4 + 1 + w;
    if (i >= SEQ_L) return;   // wave-uniform
    const size_t bb = (size_t)b * SEQ_L * DM;
    const int eo = lane * 16;

    const bf16* qrow = q + bb + (size_t)i * DM + eo;
    bf16x8 qv0 = *(const bf16x8*)(qrow);
    bf16x8 qv1 = *(const bf16x8*)(qrow + 8);

    const int4* cp = (const int4*)(ctab + i * 12);
    int4 ca = cp[0], cb = cp[1], cc = cp[2];
    int cols[11] = {ca.x, ca.y, ca.z, ca.w, cb.x, cb.y, cb.z, cb.w, cc.x, cc.y, cc.z};

    // prefetch all K rows into registers (22 independent 16B loads in flight)
    bf16x8 kv[11][2];
#pragma unroll
    for (int c = 0; c < 11; ++c) {
      int cj = cols[c] < 0 ? 0 : cols[c];
      const bf16* krow = k + bb + (size_t)cj * DM + eo;
      kv[c][0] = *(const bf16x8*)(krow);
      kv[c][1] = *(const bf16x8*)(krow + 8);
    }

    float sv[11];
#pragma unroll
    for (int c = 0; c < 11; ++c) {
      float acc = 0.f;
#pragma unroll
      for (int e = 0; e < 8; ++e)
        acc += (float)qv0[e] * (float)kv[c][0][e] + (float)qv1[e] * (float)kv[c][1][e];
      sv[c] = acc;
    }

    // issue V loads now: K registers are dead (reused for V); softmax below covers latency
    bf16x8 vv[11][2];
#pragma unroll
    for (int c = 0; c < 11; ++c) {
      int cj = cols[c] < 0 ? 0 : cols[c];
      const bf16* vrow = v + bb + (size_t)cj * DM + eo;
      vv[c][0] = *(const bf16x8*)(vrow);
      vv[c][1] = *(const bf16x8*)(vrow + 8);
    }

#pragma unroll
    for (int c = 0; c < 11; ++c) {
      sv[c] += __shfl_xor(sv[c], 1);
      sv[c] += __shfl_xor(sv[c], 2);
      sv[c] = cols[c] < 0 ? -1e30f : sv[c] * 0.125f;
    }
    float m = -1e30f;
#pragma unroll
    for (int c = 0; c < 11; ++c) m = fmaxf(m, sv[c]);
    float z = 0.f;
#pragma unroll
    for (int c = 0; c < 11; ++c) { sv[c] = __expf(sv[c] - m); z += sv[c]; }
    const float inv = 1.f / z;

    float oa[16] = {};
#pragma unroll
    for (int c = 0; c < 11; ++c) {
#pragma unroll
      for (int e = 0; e < 8; ++e) {
        oa[e]     += sv[c] * (float)vv[c][0][e];
        oa[8 + e] += sv[c] * (float)vv[c][1][e];
      }
    }
    bf16x8 ov0, ov1;
#pragma unroll
    for (int e = 0; e < 8; ++e) {
      ov0[e] = (bf16)(oa[e] * inv);
      ov1[e] = (bf16)(oa[8 + e] * inv);
    }
    bf16* orow = o + bb + (size_t)i * DM + eo;
    *(bf16x8*)(orow) = ov0;
    *(bf16x8*)(orow + 8) = ov1;
    return;
  }

  // ---- row-0 partial: (b, h, chunk of 256 cols) ----
  const int idx = blockIdx.x;           // 0..255
  const int b = idx >> 7;
  const int rem = idx & 127;
  const int h = rem >> 3;
  const int c = rem & 7;
  const size_t hb = (size_t)b * SEQ_L * DM + (size_t)h * HD;
  const int j = c * 256 + t;

  bf16x8 qv8[8];
#pragma unroll
  for (int cc = 0; cc < 8; ++cc) qv8[cc] = *(const bf16x8*)(q + hb + cc * 8);

  float acc = 0.f;
#pragma unroll
  for (int cc = 0; cc < 8; ++cc) {
    bf16x8 kv = *(const bf16x8*)(k + hb + (size_t)j * DM + cc * 8);
#pragma unroll
    for (int e = 0; e < 8; ++e) acc += (float)qv8[cc][e] * (float)kv[e];
  }
  float s = acc * 0.125f;
  float mloc = s;
#pragma unroll
  for (int off = 32; off > 0; off >>= 1) mloc = fmaxf(mloc, __shfl_xor(mloc, off));
  if (lane == 0) redm[w] = mloc;
  __syncthreads();
  const float m = fmaxf(fmaxf(redm[0], redm[1]), fmaxf(redm[2], redm[3]));

  float e = __expf(s - m);
  sbuf[t] = e;
  float zloc = e;
#pragma unroll
  for (int off = 32; off > 0; off >>= 1) zloc += __shfl_xor(zloc, off);
  if (lane == 0) redz[w] = zloc;
  __syncthreads();
  const float zc = redz[0] + redz[1] + redz[2] + redz[3];

  float oa = 0.f;
  for (int jj = w; jj < 256; jj += 4)
    oa += sbuf[jj] * (float)v[hb + (size_t)(c * 256 + jj) * DM + lane];
  part[w][lane] = oa;
  __syncthreads();
  if (t < 64) pv[idx * 64 + t] = part[0][t] + part[1][t] + part[2][t] + part[3][t];
  if (t == 0) { pm[idx] = m; pz[idx] = zc; }
}

// ---------------- launch ----------------
extern "C" void kernel_launch(void* const* d_in, const int* in_sizes, int n_in,
                              void* d_out, int out_size, void* d_ws, size_t ws_size,
                              hipStream_t stream) {
  const float* x     = (const float*)d_in[0];
  const float* freqs = (const float*)d_in[1];
  const float* wq    = (const float*)d_in[2];
  const float* wk    = (const float*)d_in[3];
  const float* wv    = (const float*)d_in[4];
  const float* wo    = (const float*)d_in[5];
  float* out = (float*)d_out;

  char* ws = (char*)d_ws;
  bf16* xb  = (bf16*)(ws + 0);          // 8 MiB
  bf16* wqb = (bf16*)(ws + 8388608);    // 2 MiB each
  bf16* wkb = (bf16*)(ws + 10485760);
  bf16* wvb = (bf16*)(ws + 12582912);
  bf16* wob = (bf16*)(ws + 14680064);
  bf16* qb  = (bf16*)(ws + 16777216);   // 8 MiB [B,L,H,HD]
  bf16* kb  = (bf16*)(ws + 25165824);
  bf16* vb  = (bf16*)(ws + 33554432);
  bf16* ab  = (bf16*)(ws + 41943040);   // 8 MiB; end 48 MiB
  int*    ctab = (int*)(ws + 50331648); // 96 KB
  float*  pm   = (float*)(ws + 50462720);
  float*  pz   = (float*)(ws + 50463744);
  float*  pv   = (float*)(ws + 50464768);   // 64 KB
  float2* rtab = (float2*)(ws + 50593792);  // 512 KB rope cos/sin table
  (void)ws_size;

  prep_kernel<<<8456, 256, 0, stream>>>(x, wq, wk, wv, wo, freqs, xb, wqb, wkb, wvb, wob, ctab, rtab);
  qkv_gemm_kernel<<<dim3(64, 16), 256, 0, stream>>>(xb, wqb, wkb, wvb, qb, kb, vb, rtab);
  attn_kernel<<<dim3(1280, 1), 256, 0, stream>>>(qb, kb, vb, ab, ctab, pm, pz, pv);
  out_gemm_kernel<<<dim3(64, 8), 256, 0, stream>>>(ab, wob, out, pm, pz, pv);
}

// Round 7
// 161.394 us; speedup vs baseline: 1.0509x; 1.0509x over previous
//
#include <hip/hip_runtime.h>
#include <math.h>

#define SEQ_L 2048
#define DM 1024
#define NH 16
#define HD 64
#define NB 2
#define KD 1024   // GEMM K
#define ND 1024   // GEMM N

typedef __bf16 bf16;
typedef __bf16 bf16x8 __attribute__((ext_vector_type(8)));
typedef __bf16 bf16x4 __attribute__((ext_vector_type(4)));
typedef __bf16 bf16x2 __attribute__((ext_vector_type(2)));
typedef float f32x4 __attribute__((ext_vector_type(4)));

// ---------------- jax threefry2x32, key = (0, 42); partitionable random_bits ----------------
__device__ inline uint32_t rotl32(uint32_t v, int n) { return (v << n) | (v >> (32 - n)); }

__device__ inline void threefry(uint32_t x0, uint32_t x1, uint32_t* o0, uint32_t* o1) {
  const uint32_t ks0 = 0u, ks1 = 42u, ks2 = 0u ^ 42u ^ 0x1BD11BDAu;
  x0 += ks0; x1 += ks1;
#define TF_R(rr) { x0 += x1; x1 = rotl32(x1, rr); x1 ^= x0; }
  TF_R(13) TF_R(15) TF_R(26) TF_R(6)
  x0 += ks1; x1 += ks2 + 1u;
  TF_R(17) TF_R(29) TF_R(16) TF_R(24)
  x0 += ks2; x1 += ks0 + 2u;
  TF_R(13) TF_R(15) TF_R(26) TF_R(6)
  x0 += ks0; x1 += ks1 + 3u;
  TF_R(17) TF_R(29) TF_R(16) TF_R(24)
  x0 += ks1; x1 += ks2 + 4u;
  TF_R(13) TF_R(15) TF_R(26) TF_R(6)
  x0 += ks2; x1 += ks0 + 5u;
#undef TF_R
  *o0 = x0; *o1 = x1;
}

// jax_threefry_partitionable=True: counter (hi=0, lo=flat_idx), bits = o0 ^ o1.
__device__ inline int rand_col(int i, int s) {
  uint32_t o0, o1;
  threefry(0u, (uint32_t)(2 * i + s), &o0, &o1);
  uint32_t bits = o0 ^ o1;
  float u = __uint_as_float((bits >> 9) | 0x3f800000u) - 1.0f;
  return (int)floorf(u * (float)(i + 1));
}

// ---------------- prep: conversions + ctab + rope cos/sin table ----------------
__global__ void prep_kernel(const float* __restrict__ x,
                            const float* __restrict__ w0, const float* __restrict__ w1,
                            const float* __restrict__ w2, const float* __restrict__ w3,
                            const float* __restrict__ freqs,
                            bf16* __restrict__ xb,
                            bf16* __restrict__ o0, bf16* __restrict__ o1,
                            bf16* __restrict__ o2, bf16* __restrict__ o3,
                            int* __restrict__ ctab, float2* __restrict__ rtab) {
  const int bx = blockIdx.x;
  const int t = threadIdx.x;
  if (bx < 8192) {
    const float* src;
    bf16* dst;
    int idx;
    if (bx < 4096) { src = x; dst = xb; idx = bx * 256 + t; }
    else {
      int widx = bx - 4096;
      int wsel = widx >> 10;
      switch (wsel) {
        case 0: src = w0; dst = o0; break;
        case 1: src = w1; dst = o1; break;
        case 2: src = w2; dst = o2; break;
        default: src = w3; dst = o3; break;
      }
      idx = (widx & 1023) * 256 + t;
    }
    float4 vv = ((const float4*)src)[idx];
    bf16x4 ov;
    ov[0] = (bf16)vv.x; ov[1] = (bf16)vv.y; ov[2] = (bf16)vv.z; ov[3] = (bf16)vv.w;
    *(bf16x4*)(dst + (size_t)idx * 4) = ov;
    return;
  }
  if (bx < 8200) {
    const int i = (bx - 8192) * 256 + t;    // 0..2047
    int cols[11]; int nc = 0;
    if (i >= 1) {
      int lo = i - 7; if (lo < 0) lo = 0;
      for (int j = lo; j <= i; ++j) cols[nc++] = j;
      if (lo > 0) cols[nc++] = 0;
#pragma unroll
      for (int s = 0; s < 2; ++s) {
        int rj = rand_col(i, s);
        bool dup = false;
        for (int c2 = 0; c2 < nc; ++c2) dup |= (cols[c2] == rj);
        if (!dup) cols[nc++] = rj;
      }
    }
    for (int c2 = nc; c2 < 11; ++c2) cols[c2] = -1;
#pragma unroll
    for (int c2 = 0; c2 < 11; ++c2) ctab[i * 12 + c2] = cols[c2];
    ctab[i * 12 + 11] = nc;
    return;
  }
  const int idx = (bx - 8200) * 256 + t;    // 0..65535
  float s, c;
  sincosf(freqs[idx], &s, &c);
  rtab[idx] = make_float2(c, s);
}

// ---------------- GEMM common ----------------
__device__ inline void gld16(const bf16* g, bf16* l) {
  __builtin_amdgcn_global_load_lds((const __attribute__((address_space(1))) void*)g,
                                   (__attribute__((address_space(3))) void*)l, 16, 0, 0);
}

// ---- fused QKV GEMM: one block = 64(m) x 64(n) tile of q, k AND v (shared A staging).
// BK=64, XOR-swizzled LDS, 32 KB total. grid (64,16) = 1024 blocks at 4 blocks/CU:
// 16 waves/CU in ONE residency pass. This is the measured 2-phase optimum for this
// geometry (~680 TF); dbuf/counted-vmcnt variants all regressed (R1/R4/R6) because
// __syncthreads drains vmcnt(0) to the NEWEST load, and 8-phase 256^2 underfills
// (192 tiles < 256 CUs). Axis closed.
__global__ __launch_bounds__(256, 4) void qkv_gemm_kernel(
    const bf16* __restrict__ xb, const bf16* __restrict__ wqb, const bf16* __restrict__ wkb,
    const bf16* __restrict__ wvb, bf16* __restrict__ qb, bf16* __restrict__ kb, bf16* __restrict__ vb,
    const float2* __restrict__ rtab) {
  __shared__ __align__(16) bf16 As[64 * 64];        // 8 KB
  __shared__ __align__(16) bf16 Bs[3][64 * 64];     // 24 KB
  const bf16* Ws[3] = {wqb, wkb, wvb};
  bf16* Ds[3] = {qb, kb, vb};

  const int t = threadIdx.x;
  const int lane = t & 63;
  const int w = t >> 6;
  const int wm = (w >> 1) * 32;     // wave tile: 32(m) x 32(n)
  const int wn = (w & 1) * 32;
  const int m0 = blockIdx.x * 64;
  const int n0 = blockIdx.y * 64;
  const int l15 = lane & 15;
  const int kq = lane >> 4;         // 0..3

  f32x4 acc[3][2][2] = {};

  for (int k0 = 0; k0 < KD; k0 += 64) {
    // A: 64x64 = 512 slots of 16B; 2 per thread
#pragma unroll
    for (int n = 0; n < 2; ++n) {
      const int s = n * 256 + t;
      const int row = s >> 3;                  // 0..63
      const int ch = (s & 7) ^ (row & 7);      // XOR bank swizzle
      gld16(xb + (size_t)(m0 + row) * KD + k0 + ch * 8, As + s * 8);
    }
    // B_j: 64x64 = 512 slots each; 2 per thread per output
#pragma unroll
    for (int j = 0; j < 3; ++j)
#pragma unroll
      for (int n = 0; n < 2; ++n) {
        const int s = n * 256 + t;
        const int row = s >> 3;                // 0..63
        const int ch = (s & 7) ^ (row & 7);
        gld16(Ws[j] + (size_t)(n0 + row) * KD + k0 + ch * 8, &Bs[j][s * 8]);
      }
    __syncthreads();
#pragma unroll
    for (int ks = 0; ks < 2; ++ks) {
      const int cb = ks * 4 + kq;              // k-chunk 0..7
      bf16x8 af[2];
#pragma unroll
      for (int mt = 0; mt < 2; ++mt) {
        const int row = wm + mt * 16 + l15;
        af[mt] = *(const bf16x8*)(As + row * 64 + ((cb ^ (row & 7)) * 8));
      }
#pragma unroll
      for (int j = 0; j < 3; ++j) {
        bf16x8 bfr[2];
#pragma unroll
        for (int nt = 0; nt < 2; ++nt) {
          const int row = wn + nt * 16 + l15;
          bfr[nt] = *(const bf16x8*)(&Bs[j][row * 64 + ((cb ^ (row & 7)) * 8)]);
        }
#pragma unroll
        for (int mt = 0; mt < 2; ++mt)
#pragma unroll
          for (int nt = 0; nt < 2; ++nt)
            acc[j][mt][nt] = __builtin_amdgcn_mfma_f32_16x16x32_bf16(af[mt], bfr[nt], acc[j][mt][nt], 0, 0, 0);
      }
    }
    __syncthreads();
  }
  // C/D layout: col = lane&15, row = (lane>>4)*4 + reg   [verified m89]
  const int colb = n0 + wn + l15;
  const int rowb = m0 + wm + (lane >> 4) * 4;
  const int odd = l15 & 1;
#pragma unroll
  for (int j = 0; j < 3; ++j) {
    bf16* D = Ds[j];
    const bool dorope = (j < 2);
#pragma unroll
    for (int mt = 0; mt < 2; ++mt)
#pragma unroll
      for (int nt = 0; nt < 2; ++nt) {
        const int col = colb + nt * 16;
        const int jj = (col & 63) >> 1;
#pragma unroll
        for (int rr = 0; rr < 4; ++rr) {
          float val = acc[j][mt][nt][rr];
          float other = __shfl_xor(val, 1);    // partner column value
          if (!odd) {
            const int row = rowb + mt * 16 + rr;
            float lo, hi;
            if (dorope) {
              float2 cs = rtab[(row & (SEQ_L - 1)) * 32 + jj];
              lo = val * cs.x - other * cs.y;  // out_re
              hi = val * cs.y + other * cs.x;  // out_im
            } else { lo = val; hi = other; }
            bf16x2 p; p[0] = (bf16)lo; p[1] = (bf16)hi;
            *(bf16x2*)(D + (size_t)row * ND + col) = p;
          }
        }
      }
  }
}

// ---- out-projection GEMM: 64x128 tile, BK=64, swizzled; grid (64,8) = 512 blocks ----
// Blocks x==0 / x==32 first materialize row-0 attention output from (pm,pz,pv).
__global__ __launch_bounds__(256, 2) void out_gemm_kernel(
    bf16* __restrict__ ab, const bf16* __restrict__ wob, float* __restrict__ out,
    const float* __restrict__ pm, const float* __restrict__ pz, const float* __restrict__ pv) {
  const int t = threadIdx.x;
  const int m0 = blockIdx.x * 64;
  const int n0 = blockIdx.y * 128;

  if (blockIdx.x == 0 || blockIdx.x == 32) {
    const int b = blockIdx.x == 0 ? 0 : 1;
#pragma unroll
    for (int e = t; e < DM; e += 256) {
      const int h = e >> 6, d = e & 63;
      const int base = b * 128 + h * 8;
      float M = -1e30f;
#pragma unroll
      for (int c = 0; c < 8; ++c) M = fmaxf(M, pm[base + c]);
      float Z = 0.f, od = 0.f;
#pragma unroll
      for (int c = 0; c < 8; ++c) {
        float sc = __expf(pm[base + c] - M);
        Z += pz[base + c] * sc;
        od += pv[(base + c) * 64 + d] * sc;
      }
      ab[(size_t)b * SEQ_L * DM + e] = (bf16)(od / Z);
    }
    __syncthreads();   // drain stores before staging reads the same row
  }

  __shared__ __align__(16) bf16 As[64 * 64];    // 8 KB
  __shared__ __align__(16) bf16 Bs[128 * 64];   // 16 KB
  const int lane = t & 63;
  const int wave = t >> 6;
  const int wm = (wave >> 1) * 32;
  const int wn = (wave & 1) * 64;
  const int l15 = lane & 15;
  const int kq = lane >> 4;

  f32x4 acc[2][4] = {};

  for (int k0 = 0; k0 < KD; k0 += 64) {
#pragma unroll
    for (int n = 0; n < 2; ++n) {
      const int s = n * 256 + t;               // 512 slots for As
      const int row = s >> 3;                  // 0..63
      const int ch = (s & 7) ^ (row & 7);
      gld16(ab + (size_t)(m0 + row) * KD + k0 + ch * 8, As + s * 8);
    }
#pragma unroll
    for (int n = 0; n < 4; ++n) {
      const int s = n * 256 + t;               // 1024 slots for Bs
      const int row = s >> 3;                  // 0..127
      const int ch = (s & 7) ^ (row & 7);
      gld16(wob + (size_t)(n0 + row) * KD + k0 + ch * 8, Bs + s * 8);
    }
    __syncthreads();
#pragma unroll
    for (int ks = 0; ks < 2; ++ks) {
      const int cb = ks * 4 + kq;
      bf16x8 af[2], bfr[4];
#pragma unroll
      for (int mt = 0; mt < 2; ++mt) {
        const int row = wm + mt * 16 + l15;
        af[mt] = *(const bf16x8*)(As + row * 64 + ((cb ^ (row & 7)) * 8));
      }
#pragma unroll
      for (int nt = 0; nt < 4; ++nt) {
        const int row = wn + nt * 16 + l15;
        bfr[nt] = *(const bf16x8*)(Bs + row * 64 + ((cb ^ (row & 7)) * 8));
      }
#pragma unroll
      for (int mt = 0; mt < 2; ++mt)
#pragma unroll
        for (int nt = 0; nt < 4; ++nt)
          acc[mt][nt] = __builtin_amdgcn_mfma_f32_16x16x32_bf16(af[mt], bfr[nt], acc[mt][nt], 0, 0, 0);
    }
    __syncthreads();
  }
  const int colb = n0 + wn + l15;
  const int rowb = m0 + wm + (lane >> 4) * 4;
#pragma unroll
  for (int mt = 0; mt < 2; ++mt)
#pragma unroll
    for (int nt = 0; nt < 4; ++nt)
#pragma unroll
      for (int rr = 0; rr < 4; ++rr)
        out[(size_t)(rowb + mt * 16 + rr) * ND + colb + nt * 16] = acc[mt][nt][rr];
}

// ---------------- attention ----------------
// grid (1280, 1), 256 threads.
//  bx < 256  : row-0 partials per (b, h, 256-col chunk) -> pm/pz/pv (dispatched FIRST: no tail).
//  bx >= 256 : sparse rows; wave handles one row i for ALL 16 heads (2KB wave-loads).
//  T14-lite: K quads prefetched up-front; V loads issued AFTER the QK dots so the
//  allocator reuses K's ~88 VGPRs for V -> __launch_bounds__(256,3) = 12 waves/CU.
__global__ __launch_bounds__(256, 3) void attn_kernel(const bf16* __restrict__ q, const bf16* __restrict__ k,
                                                      const bf16* __restrict__ v, bf16* __restrict__ o,
                                                      const int* __restrict__ ctab,
                                                      float* __restrict__ pm, float* __restrict__ pz,
                                                      float* __restrict__ pv) {
  const int t = threadIdx.x;
  const int lane = t & 63;
  const int w = t >> 6;

  __shared__ float sbuf[256];
  __shared__ float redm[4], redz[4];
  __shared__ float part[4][64];

  if (blockIdx.x >= 256) {
    const int sbx = blockIdx.x - 256;               // 0..1023
    const int b = sbx >> 9;
    const int tt = sbx & 511;
    const int tile = ((tt & 7) << 6) + (tt >> 3);   // XCD swizzle
    const int i = tile * 4 + 1 + w;
    if (i >= SEQ_L) return;   // wave-uniform
    const size_t bb = (size_t)b * SEQ_L * DM;
    const int eo = lane * 16;

    const bf16* qrow = q + bb + (size_t)i * DM + eo;
    bf16x8 qv0 = *(const bf16x8*)(qrow);
    bf16x8 qv1 = *(const bf16x8*)(qrow + 8);

    const int4* cp = (const int4*)(ctab + i * 12);
    int4 ca = cp[0], cb = cp[1], cc = cp[2];
    int cols[11] = {ca.x, ca.y, ca.z, ca.w, cb.x, cb.y, cb.z, cb.w, cc.x, cc.y, cc.z};

    // prefetch all K rows into registers (22 independent 16B loads in flight)
    bf16x8 kv[11][2];
#pragma unroll
    for (int c = 0; c < 11; ++c) {
      int cj = cols[c] < 0 ? 0 : cols[c];
      const bf16* krow = k + bb + (size_t)cj * DM + eo;
      kv[c][0] = *(const bf16x8*)(krow);
      kv[c][1] = *(const bf16x8*)(krow + 8);
    }

    float sv[11];
#pragma unroll
    for (int c = 0; c < 11; ++c) {
      float acc = 0.f;
#pragma unroll
      for (int e = 0; e < 8; ++e)
        acc += (float)qv0[e] * (float)kv[c][0][e] + (float)qv1[e] * (float)kv[c][1][e];
      sv[c] = acc;
    }

    // issue V loads now: K registers are dead (reused for V); softmax below covers latency
    bf16x8 vv[11][2];
#pragma unroll
    for (int c = 0; c < 11; ++c) {
      int cj = cols[c] < 0 ? 0 : cols[c];
      const bf16* vrow = v + bb + (size_t)cj * DM + eo;
      vv[c][0] = *(const bf16x8*)(vrow);
      vv[c][1] = *(const bf16x8*)(vrow + 8);
    }

#pragma unroll
    for (int c = 0; c < 11; ++c) {
      sv[c] += __shfl_xor(sv[c], 1);
      sv[c] += __shfl_xor(sv[c], 2);
      sv[c] = cols[c] < 0 ? -1e30f : sv[c] * 0.125f;
    }
    float m = -1e30f;
#pragma unroll
    for (int c = 0; c < 11; ++c) m = fmaxf(m, sv[c]);
    float z = 0.f;
#pragma unroll
    for (int c = 0; c < 11; ++c) { sv[c] = __expf(sv[c] - m); z += sv[c]; }
    const float inv = 1.f / z;

    float oa[16] = {};
#pragma unroll
    for (int c = 0; c < 11; ++c) {
#pragma unroll
      for (int e = 0; e < 8; ++e) {
        oa[e]     += sv[c] * (float)vv[c][0][e];
        oa[8 + e] += sv[c] * (float)vv[c][1][e];
      }
    }
    bf16x8 ov0, ov1;
#pragma unroll
    for (int e = 0; e < 8; ++e) {
      ov0[e] = (bf16)(oa[e] * inv);
      ov1[e] = (bf16)(oa[8 + e] * inv);
    }
    bf16* orow = o + bb + (size_t)i * DM + eo;
    *(bf16x8*)(orow) = ov0;
    *(bf16x8*)(orow + 8) = ov1;
    return;
  }

  // ---- row-0 partial: (b, h, chunk of 256 cols) ----
  const int idx = blockIdx.x;           // 0..255
  const int b = idx >> 7;
  const int rem = idx & 127;
  const int h = rem >> 3;
  const int c = rem & 7;
  const size_t hb = (size_t)b * SEQ_L * DM + (size_t)h * HD;
  const int j = c * 256 + t;

  bf16x8 qv8[8];
#pragma unroll
  for (int cc = 0; cc < 8; ++cc) qv8[cc] = *(const bf16x8*)(q + hb + cc * 8);

  float acc = 0.f;
#pragma unroll
  for (int cc = 0; cc < 8; ++cc) {
    bf16x8 kv = *(const bf16x8*)(k + hb + (size_t)j * DM + cc * 8);
#pragma unroll
    for (int e = 0; e < 8; ++e) acc += (float)qv8[cc][e] * (float)kv[e];
  }
  float s = acc * 0.125f;
  float mloc = s;
#pragma unroll
  for (int off = 32; off > 0; off >>= 1) mloc = fmaxf(mloc, __shfl_xor(mloc, off));
  if (lane == 0) redm[w] = mloc;
  __syncthreads();
  const float m = fmaxf(fmaxf(redm[0], redm[1]), fmaxf(redm[2], redm[3]));

  float e = __expf(s - m);
  sbuf[t] = e;
  float zloc = e;
#pragma unroll
  for (int off = 32; off > 0; off >>= 1) zloc += __shfl_xor(zloc, off);
  if (lane == 0) redz[w] = zloc;
  __syncthreads();
  const float zc = redz[0] + redz[1] + redz[2] + redz[3];

  float oa = 0.f;
  for (int jj = w; jj < 256; jj += 4)
    oa += sbuf[jj] * (float)v[hb + (size_t)(c * 256 + jj) * DM + lane];
  part[w][lane] = oa;
  __syncthreads();
  if (t < 64) pv[idx * 64 + t] = part[0][t] + part[1][t] + part[2][t] + part[3][t];
  if (t == 0) { pm[idx] = m; pz[idx] = zc; }
}

// ---------------- launch ----------------
extern "C" void kernel_launch(void* const* d_in, const int* in_sizes, int n_in,
                              void* d_out, int out_size, void* d_ws, size_t ws_size,
                              hipStream_t stream) {
  const float* x     = (const float*)d_in[0];
  const float* freqs = (const float*)d_in[1];
  const float* wq    = (const float*)d_in[2];
  const float* wk    = (const float*)d_in[3];
  const float* wv    = (const float*)d_in[4];
  const float* wo    = (const float*)d_in[5];
  float* out = (float*)d_out;

  char* ws = (char*)d_ws;
  bf16* xb  = (bf16*)(ws + 0);          // 8 MiB
  bf16* wqb = (bf16*)(ws + 8388608);    // 2 MiB each
  bf16* wkb = (bf16*)(ws + 10485760);
  bf16* wvb = (bf16*)(ws + 12582912);
  bf16* wob = (bf16*)(ws + 14680064);
  bf16* qb  = (bf16*)(ws + 16777216);   // 8 MiB [B,L,H,HD]
  bf16* kb  = (bf16*)(ws + 25165824);
  bf16* vb  = (bf16*)(ws + 33554432);
  bf16* ab  = (bf16*)(ws + 41943040);   // 8 MiB; end 48 MiB
  int*    ctab = (int*)(ws + 50331648); // 96 KB
  float*  pm   = (float*)(ws + 50462720);
  float*  pz   = (float*)(ws + 50463744);
  float*  pv   = (float*)(ws + 50464768);   // 64 KB
  float2* rtab = (float2*)(ws + 50593792);  // 512 KB rope cos/sin table
  (void)ws_size;

  prep_kernel<<<8456, 256, 0, stream>>>(x, wq, wk, wv, wo, freqs, xb, wqb, wkb, wvb, wob, ctab, rtab);
  qkv_gemm_kernel<<<dim3(64, 16), 256, 0, stream>>>(xb, wqb, wkb, wvb, qb, kb, vb, rtab);
  attn_kernel<<<dim3(1280, 1), 256, 0, stream>>>(qb, kb, vb, ab, ctab, pm, pz, pv);
  out_gemm_kernel<<<dim3(64, 8), 256, 0, stream>>>(ab, wob, out, pm, pz, pv);
}